// Round 3
// baseline (303.813 us; speedup 1.0000x reference)
//
#include <hip/hip_runtime.h>

// CSTR gated-estimator trajectory cost — 2 lanes per sample, chain-optimized.
// Regime (established R1/R2): per-sample dependent-chain latency bound.
// Total time = T * per-step(issue + exposed chain) of one wave; occupancy is
// irrelevant (all samples already parallel). So: minimize the per-step chain.
//
// Chain cuts vs R2:
//  - u = K·xh_new = kxh + d*(kx - kxh): both dot products delta-independent,
//    post-delta tail is 1 FMA (+1 add for x) instead of xh->u->x nest.
//  - hu_t = Hs*K·xh_{t+1} IS next step's hkxh -> carried, not recomputed.
//  - control cost accumulated in Hs-scaled domain: sum (Hs*K·x)^2, scaled by
//    R/H^2 = 1000 at the end (reuses the hkx dot product).
// RK4 collapsed analytically (affine plant), sigmoid in exp2 domain with
// -log2(e) folded into the phi coefficients (R2, unchanged).

#define T_STEPS 2048
#define BATCH   8192

__device__ __forceinline__ float swapf(float v) {
    // quad_perm [1,0,3,2]: swap adjacent lane pairs.
    return __int_as_float(__builtin_amdgcn_update_dpp(
        0, __float_as_int(v), 0xB1, 0xF, 0xF, true));
}

__global__ __launch_bounds__(64, 1) void cstr_kernel(
    const float* __restrict__ w,   // (B, 2, T)
    const float* __restrict__ K,   // (1, 2)
    const float* __restrict__ L,   // (4, 4)
    const float* __restrict__ M,   // (1, 4)
    const float* __restrict__ Mo,  // (1, 1)
    float* __restrict__ out)       // (B,)
{
    const int lane = threadIdx.x;
    const int p = lane & 1;                          // owned state index
    const int s = blockIdx.x * 32 + (lane >> 1);     // sample id

    // ---- uniform scalars ----
    const float k1c = K[0], k2c = K[1];
    const float s11 = L[0];
    const float s12 = L[1] + L[4];
    const float s13 = L[2] + L[8];
    const float s14 = L[3] + L[12];
    const float s22 = L[5];
    const float s23 = L[6] + L[9];
    const float s24 = L[7] + L[13];
    const float s33 = L[10];
    const float s34 = L[11] + L[14];
    const float s44 = L[15];
    const float m1 = M[0], m2 = M[1], m3 = M[2], m4 = M[3];
    const float c0 = Mo[0];

    constexpr float Hs = 0.01f;
    constexpr float Ad = 1.0f - 2.0f * Hs;           // 0.98
    constexpr float RU = 0.1f / (Hs * Hs);           // R / H^2 = 1000
    constexpr float SC = -1.44269504088896340736f;   // -log2(e)

    // ---- per-lane constants (phi partial, lane-split quadratic form) ----
    float P1, P2, P3, P4, P5, P6, P7, P8;
    if (p == 0) { P1 = s11; P2 = s12; P3 = s13; P4 = s14; P5 = m1; P6 = s33; P7 = s34; P8 = m3; }
    else        { P1 = s22; P2 = 0.f; P3 = s24; P4 = s23; P5 = m2; P6 = s44; P7 = 0.f; P8 = m4; }
    P1 *= SC; P2 *= SC; P3 *= SC; P4 *= SC; P5 *= SC; P6 *= SC; P7 *= SC; P8 *= SC;
    const float P9 = 0.5f * c0 * SC;

    const float hk   = Hs * (p ? k2c : k1c);          // Hs * K_own
    const float Cown = p ? (-Hs * Hs) : (0.5f * Hs * Hs);

    // ---- state ----
    float x  = p ? 0.0f : 1.0f;     // x0 = (1, 0)
    float xh = x;
    float hkxh = Hs * k1c;          // Hs * K·xh0, carried forward as hu_t
    float accO = 0.0f;              // own-state sum x^2
    float accU = 0.0f;              // sum (Hs*K·x)^2  (scaled control cost)
    float accD = 0.0f;              // sum delta

    auto step = [&](float wv, bool first, bool cost) {
        float xo  = swapf(x);
        float xho = swapf(xh);
        // ---- delta-independent work (fills the exp/rcp stall window) ----
        float hkx_h = hk * x;
        float hkx   = hkx_h + swapf(hkx_h);            // Hs * K·x
        float base  = fmaf(Ad, x, fmaf(Hs, xo, wv + Cown));
        float dxh   = x - xh;
        float dk    = hkx - hkxh;
        if (cost) {
            accO = fmaf(x, x, accO);
            accU = fmaf(hkx, hkx, accU);
        }
        // ---- gate chain: phi -> exp2 -> rcp ----
        float d;
        if (first) {
            d = 1.0f;              // i==0: gate forced (x==xh, xh frozen)
        } else {
            float t  = fmaf(P2, xo, fmaf(P1, x, P5));
            t        = fmaf(P3, xh, t);
            t        = fmaf(P4, xho, t);
            float u2 = fmaf(P7, xho, fmaf(P6, xh, P8));
            float part = fmaf(xh, u2, fmaf(x, t, P9));
            float e  = __builtin_amdgcn_exp2f(part + swapf(part)); // exp(-phi)
            d        = __builtin_amdgcn_rcpf(1.0f + e);
        }
        if (cost) accD += d;
        // ---- short post-delta tail ----
        xh = fmaf(d, dxh, xh);
        float hu = fmaf(d, dk, hkxh);  // Hs * K·xh_new
        hkxh = hu;                     // carry: next step's Hs*K·xh
        x = base + hu;
    };

    auto chunk = [&](const float4* buf, bool first, bool lastchunk) {
        #pragma unroll
        for (int q = 0; q < 4; ++q) {
            float4 a = buf[q];
            step(a.x, first && (q == 0), true);
            step(a.y, false, true);
            step(a.z, false, true);
            step(a.w, false, !(lastchunk && (q == 3)));  // t=T-1: no stage cost
        }
    };

    // own-row stream: T floats = 512 float4 = 128 chunks of 16 steps
    const float4* r = reinterpret_cast<const float4*>(
        w + ((size_t)s * 2 + p) * T_STEPS);

    float4 Abuf[4], Bbuf[4];
    #pragma unroll
    for (int q = 0; q < 4; ++q) Abuf[q] = r[q];        // chunk 0
    #pragma unroll
    for (int q = 0; q < 4; ++q) Bbuf[q] = r[4 + q];    // chunk 1

    chunk(Abuf, true, false);                          // chunk 0 (step 0 special)

    for (int i = 0; i < 63; ++i) {                     // chunks 1..126
        const float4* pa = r + (size_t)(2 + 2 * i) * 4;
        #pragma unroll
        for (int q = 0; q < 4; ++q) Abuf[q] = pa[q];   // prefetch chunk 2+2i
        chunk(Bbuf, false, false);                     // process chunk 1+2i
        const float4* pb = r + (size_t)(3 + 2 * i) * 4;
        #pragma unroll
        for (int q = 0; q < 4; ++q) Bbuf[q] = pb[q];   // prefetch chunk 3+2i
        chunk(Abuf, false, false);                     // process chunk 2+2i
    }
    chunk(Bbuf, false, true);                          // chunk 127 (t=T-1: no cost)

    // terminal cost 10*(x1^2 + x2^2), split by ownership; unscale control cost
    accO = fmaf(10.0f * x, x, accO);
    float J = accO + swapf(accO) + fmaf(RU, accU, accD);
    if (p == 0) out[s] = J;
}

extern "C" void kernel_launch(void* const* d_in, const int* in_sizes, int n_in,
                              void* d_out, int out_size, void* d_ws, size_t ws_size,
                              hipStream_t stream) {
    const float* w  = (const float*)d_in[0];
    const float* K  = (const float*)d_in[1];
    const float* L  = (const float*)d_in[2];
    const float* M  = (const float*)d_in[3];
    const float* Mo = (const float*)d_in[4];
    float* out = (float*)d_out;

    // 8192 samples * 2 lanes = 16384 threads = 256 blocks of 64 (1 wave each)
    hipLaunchKernelGGL(cstr_kernel, dim3(BATCH * 2 / 64), dim3(64), 0, stream,
                       w, K, L, M, Mo, out);
}